// Round 4
// baseline (415.415 us; speedup 1.0000x reference)
//
#include <hip/hip_runtime.h>
#include <hip/hip_bf16.h>
#include <math.h>

typedef __hip_bfloat16 bf16;
typedef __attribute__((ext_vector_type(8))) __bf16 bf16x8;
typedef __attribute__((ext_vector_type(4))) float f32x4;

#define KIN 512
#define F1  256
#define F2  16
#define F3  40
#define NBIN 64

// ---------------- helpers ----------------

__device__ inline unsigned pk_bf2(float a, float b) {
  bf16 x = __float2bfloat16(a), y = __float2bfloat16(b);
  unsigned short ux = *(unsigned short*)&x, uy = *(unsigned short*)&y;
  return (unsigned)ux | ((unsigned)uy << 16);
}
__device__ inline float bfbits(unsigned u16) {
  unsigned v = u16 << 16;
  return *(float*)&v;
}
__device__ inline void async16(const void* g, void* l) {
  __builtin_amdgcn_global_load_lds((const __attribute__((address_space(1))) void*)g,
                                   (__attribute__((address_space(3))) void*)l, 16, 0, 0);
}
__device__ inline void accum8(float* acc, uint4 h, float w) {
  acc[0] = fmaf(w, bfbits(h.x & 0xffff), acc[0]);
  acc[1] = fmaf(w, bfbits(h.x >> 16),    acc[1]);
  acc[2] = fmaf(w, bfbits(h.y & 0xffff), acc[2]);
  acc[3] = fmaf(w, bfbits(h.y >> 16),    acc[3]);
  acc[4] = fmaf(w, bfbits(h.z & 0xffff), acc[4]);
  acc[5] = fmaf(w, bfbits(h.z >> 16),    acc[5]);
  acc[6] = fmaf(w, bfbits(h.w & 0xffff), acc[6]);
  acc[7] = fmaf(w, bfbits(h.w >> 16),    acc[7]);
}

// ---------------- init: zero cnt + hist + flag + W1 transpose (fused) ------

__global__ __launch_bounds__(256) void k_init2(int* __restrict__ cnt,
                                               const int* __restrict__ ei, int* __restrict__ flag,
                                               const float* __restrict__ W,
                                               unsigned short* __restrict__ Wt,
                                               int* __restrict__ hist,
                                               int n, int nb) {
  int b = blockIdx.x;
  int t = threadIdx.x;
  if (b < nb) {
    int i = b * 256 + t;
    if (i < n) cnt[i] = 0;
    if (b == 0 && t < NBIN) hist[t] = 0;
    if (b == 0 && t == 0)
      *flag = (ei[1] == 0 && ei[3] == 0 && ei[5] == 0 && ei[7] == 0) ? 1 : 0;
  } else {
    __shared__ float tile[32][33];
    int b2 = b - nb;
    int k0 = (b2 & 15) * 32;
    int n0 = (b2 >> 4) * 32;
    int lr = t >> 5, lc = t & 31;
#pragma unroll
    for (int rr = 0; rr < 32; rr += 8)
      tile[lr + rr][lc] = W[(size_t)(k0 + lr + rr) * F1 + n0 + lc];
    __syncthreads();
#pragma unroll
    for (int rr = 0; rr < 32; rr += 8) {
      bf16 v = __float2bfloat16(tile[lc][lr + rr]);
      Wt[(size_t)(n0 + lr + rr) * KIN + k0 + lc] = *(unsigned short*)&v;
    }
  }
}

// ---- count (atomic, returns rank) -----------------------------------------

__global__ __launch_bounds__(256) void k_count(const int* __restrict__ ei,
                                               const int* __restrict__ flag,
                                               int* __restrict__ cnt,
                                               int* __restrict__ rank, int E) {
  int e = blockIdx.x * 256 + threadIdx.x;
  if (e >= E) return;
  int is64 = *flag;
  int d = is64 ? ei[2 * E + 2 * e] : ei[E + e];
  rank[e] = atomicAdd(&cnt[d], 1);
}

__global__ __launch_bounds__(256) void k_scan1(const int* __restrict__ cnt,
                                               int* __restrict__ off,
                                               int* __restrict__ bsum,
                                               float* __restrict__ dinv,
                                               int* __restrict__ hist, int N) {
  __shared__ int s[256];
  __shared__ int lh[NBIN];
  int t = threadIdx.x;
  if (t < NBIN) lh[t] = 0;
  int base = blockIdx.x * 1024 + t * 4;
  int v0 = (base + 0 < N) ? cnt[base + 0] : 0;
  int v1 = (base + 1 < N) ? cnt[base + 1] : 0;
  int v2 = (base + 2 < N) ? cnt[base + 2] : 0;
  int v3 = (base + 3 < N) ? cnt[base + 3] : 0;
  if (base + 0 < N) dinv[base + 0] = rsqrtf((float)(v0 + 1));
  if (base + 1 < N) dinv[base + 1] = rsqrtf((float)(v1 + 1));
  if (base + 2 < N) dinv[base + 2] = rsqrtf((float)(v2 + 1));
  if (base + 3 < N) dinv[base + 3] = rsqrtf((float)(v3 + 1));
  int tsum = v0 + v1 + v2 + v3;
  s[t] = tsum;
  __syncthreads();
  // degree histogram (LDS-aggregated, lh zeroed before the sync above)
  if (base + 0 < N) atomicAdd(&lh[v0 < 63 ? v0 : 63], 1);
  if (base + 1 < N) atomicAdd(&lh[v1 < 63 ? v1 : 63], 1);
  if (base + 2 < N) atomicAdd(&lh[v2 < 63 ? v2 : 63], 1);
  if (base + 3 < N) atomicAdd(&lh[v3 < 63 ? v3 : 63], 1);
  for (int d = 1; d < 256; d <<= 1) {
    int u = (t >= d) ? s[t - d] : 0;
    __syncthreads();
    s[t] += u;
    __syncthreads();
  }
  int excl = s[t] - tsum;
  int p0 = excl + v0, p1 = p0 + v1, p2 = p1 + v2, p3 = p2 + v3;
  if (base + 0 < N) off[base + 1] = p0;
  if (base + 1 < N) off[base + 2] = p1;
  if (base + 2 < N) off[base + 3] = p2;
  if (base + 3 < N) off[base + 4] = p3;
  if (t == 255) bsum[blockIdx.x] = s[255];
  // last scan-loop __syncthreads() ordered all lh atomics before this read
  if (t < NBIN) {
    int h = lh[t];
    if (h) atomicAdd(&hist[t], h);
  }
}

// scan3 with inlined carry reduction + DESCENDING degree-bin exclusive scan
// (high-degree nodes first in perm -> heavy blocks launch first, no drain tail)
__global__ __launch_bounds__(256) void k_scan3m(int* __restrict__ off,
                                                const int* __restrict__ bsum,
                                                const int* __restrict__ hist,
                                                int* __restrict__ binoff, int N) {
  __shared__ int cs;
  int t = threadIdx.x;
  if (t < 64) {
    int v = (t < blockIdx.x) ? bsum[t] : 0;   // blockIdx.x <= 49 < 64
    for (int d = 32; d; d >>= 1) v += __shfl_xor(v, d, 64);
    if (t == 0) cs = v;
  }
  if (blockIdx.x == 0 && t < NBIN) {
    int a = 0;
    for (int j = t + 1; j < NBIN; ++j) a += hist[j];
    binoff[t] = a;
  }
  __syncthreads();
  int c = cs;
  int base = blockIdx.x * 1024 + t * 4;
#pragma unroll
  for (int k = 0; k < 4; ++k)
    if (base + k < N) off[base + k + 1] += c;
  if (blockIdx.x == 0 && t == 0) off[0] = 0;
}

// -------- GEMM1 (A = x f32, converted in-staging) + scatter + perm-build ---
// A-path: reg-staged f32 loads of x, packed to bf16 with the same RNE
// conversion as before (h1 bit-identical), written to the chunk-XOR LDS
// layout via ds_write_b128. B-path keeps global_load_lds. Kills the 102 MB
// xb round trip.

__global__ __launch_bounds__(256) void k_gemm1_sc(const float* __restrict__ X,
                                                  const unsigned short* __restrict__ Bt,
                                                  bf16* __restrict__ C, int M, int ngx,
                                                  const int* __restrict__ ei,
                                                  const int* __restrict__ flag,
                                                  const int* __restrict__ off,
                                                  const int* __restrict__ rank,
                                                  const float* __restrict__ dinv,
                                                  int2* __restrict__ ew, int E, int ebk,
                                                  const int* __restrict__ cnt,
                                                  int* __restrict__ binoff,
                                                  int* __restrict__ perm) {
  __shared__ __align__(16) unsigned short As[128 * 32];
  __shared__ __align__(16) unsigned short Bs[128 * 32];
  __shared__ int lh[NBIN], lb[NBIN];
  int b = blockIdx.x;
  int t = threadIdx.x;
  int ngemm = ngx * 2;
  if (b >= ngemm + ebk) {
    // ---- perm-build role: counting-sort scatter (nodes sorted by degree) ----
    int idx = (b - ngemm - ebk) * 256 + t;
    if (t < NBIN) lh[t] = 0;
    __syncthreads();
    int bin = 0, lr2 = 0;
    bool valid = (idx < M);
    if (valid) {
      int d = cnt[idx];
      bin = d < 63 ? d : 63;
      lr2 = atomicAdd(&lh[bin], 1);
    }
    __syncthreads();
    if (t < NBIN && lh[t] > 0) lb[t] = atomicAdd(&binoff[t], lh[t]);
    __syncthreads();
    if (valid) perm[lb[bin] + lr2] = idx;
    return;
  }
  if (b >= ngemm) {
    // ---- scatter role (atomic-free) ----
    int e = (b - ngemm) * 256 + t;
    if (e >= E) return;
    int is64 = *flag;
    int s, d;
    if (is64) { s = ei[2 * e]; d = ei[2 * E + 2 * e]; }
    else      { s = ei[e];     d = ei[E + e]; }
    int pos = off[d] + rank[e];
    float w = dinv[s] * dinv[d];
    ew[pos] = make_int2(s, __float_as_int(w));
    return;
  }
  // ---- gemm role ----
  int wave = t >> 6, lane = t & 63;
  int wm = wave >> 1, wn = wave & 1;
  int row0 = (b % ngx) * 128, col0 = (b / ngx) * 128;
  int q = lane >> 4, m16 = lane & 15;
  int srow = lane >> 2, schk = lane & 3;

  // A-staging assignment: thread t covers slots (r, s0) and (r, s0+1),
  // r = t>>1, s0 = (t&1)*2. Slot (r,s) holds global chunk g = s ^ ((r>>1)&3).
  int ar = t >> 1;
  int as0 = (t & 1) * 2;
  int agr = row0 + ar; if (agr >= M) agr = M - 1;
  int ag0 = as0 ^ ((ar >> 1) & 3);
  int ag1 = (as0 + 1) ^ ((ar >> 1) & 3);
  const float* xrow = X + (size_t)agr * KIN;
  uint4* aslot0 = (uint4*)(As + ar * 32 + as0 * 8);
  uint4* aslot1 = (uint4*)(As + ar * 32 + (as0 + 1) * 8);

  f32x4 acc[4][4];
#pragma unroll
  for (int i = 0; i < 4; ++i)
#pragma unroll
    for (int j = 0; j < 4; ++j) acc[i][j] = {0.f, 0.f, 0.f, 0.f};

  for (int kb = 0; kb < 16; ++kb) {
    __syncthreads();
    // A: 4 f32x4 loads (issue first, fly under B-issue + pack)
    const float4* pa0 = (const float4*)(xrow + kb * 32 + ag0 * 8);
    const float4* pa1 = (const float4*)(xrow + kb * 32 + ag1 * 8);
    float4 a00 = pa0[0], a01 = pa0[1];
    float4 a10 = pa1[0], a11 = pa1[1];
    // B: async global->LDS (unchanged)
#pragma unroll
    for (int jj = 0; jj < 2; ++jj) {
      int lr = wave * 32 + jj * 16 + srow;
      int gchk = schk ^ ((lr >> 1) & 3);
      async16(Bt + (size_t)(col0 + lr) * KIN + kb * 32 + gchk * 8,
              Bs + (wave * 32 + jj * 16) * 32);
    }
    // pack A to bf16 and store to swizzled slots
    uint4 w0, w1;
    w0.x = pk_bf2(a00.x, a00.y); w0.y = pk_bf2(a00.z, a00.w);
    w0.z = pk_bf2(a01.x, a01.y); w0.w = pk_bf2(a01.z, a01.w);
    w1.x = pk_bf2(a10.x, a10.y); w1.y = pk_bf2(a10.z, a10.w);
    w1.z = pk_bf2(a11.x, a11.y); w1.w = pk_bf2(a11.z, a11.w);
    *aslot0 = w0;
    *aslot1 = w1;
    __syncthreads();
    bf16x8 af[4], bfr[4];
#pragma unroll
    for (int i = 0; i < 4; ++i) {
      int m = wm * 64 + i * 16 + m16;
      af[i] = *(const bf16x8*)(As + m * 32 + ((q ^ ((m >> 1) & 3)) * 8));
    }
#pragma unroll
    for (int j = 0; j < 4; ++j) {
      int n = wn * 64 + j * 16 + m16;
      bfr[j] = *(const bf16x8*)(Bs + n * 32 + ((q ^ ((n >> 1) & 3)) * 8));
    }
#pragma unroll
    for (int j = 0; j < 4; ++j)
#pragma unroll
      for (int i = 0; i < 4; ++i)
        acc[i][j] = __builtin_amdgcn_mfma_f32_16x16x32_bf16(af[i], bfr[j], acc[i][j], 0, 0, 0);
  }

#pragma unroll
  for (int i = 0; i < 4; ++i) {
#pragma unroll
    for (int r = 0; r < 4; ++r) {
      int row = row0 + wm * 64 + i * 16 + q * 4 + r;
      if (row < M) {
#pragma unroll
        for (int j = 0; j < 4; ++j) {
          int col = col0 + wn * 64 + j * 16 + m16;
          C[(size_t)row * F1 + col] = __float2bfloat16(acc[i][j][r]);
        }
      }
    }
  }
}

// ------- Fused Aggregation L1 + ReLU + GEMM2: zero LDS, zero barriers ------
// 8 nodes/block, 32 lanes/node (lane owns 8 feats). Gather full 512B rows.
// Projection to 16 cols done per-lane vs L1-resident W2 (128 FMA), then a
// 31-shuffle fold across the node's 32 lanes that reduces AND redistributes:
// lane gl ends holding column gl&15. Waves fully independent -> max TLP.

__global__ __launch_bounds__(256) void k_agg1g2(const bf16* __restrict__ H,
                                                const int* __restrict__ off,
                                                const int2* __restrict__ ew,
                                                const float* __restrict__ dinv,
                                                const float* __restrict__ b1,
                                                const int* __restrict__ perm,
                                                const float* __restrict__ W2,
                                                float* __restrict__ h2, int N) {
  int t = threadIdx.x;
  int idx = blockIdx.x * 8 + (t >> 5);          // uniform per 32-lane group
  int cidx = idx < N ? idx : N - 1;
  int i = perm[cidx];
  int gl = t & 31;
  int f0 = gl * 8;
  const unsigned short* Hu = (const unsigned short*)H;
  float di = dinv[i];
  float w0 = di * di;
  float acc[8];
  {
    uint4 h = *(const uint4*)(Hu + (size_t)i * F1 + f0);
    acc[0] = w0 * bfbits(h.x & 0xffff); acc[1] = w0 * bfbits(h.x >> 16);
    acc[2] = w0 * bfbits(h.y & 0xffff); acc[3] = w0 * bfbits(h.y >> 16);
    acc[4] = w0 * bfbits(h.z & 0xffff); acc[5] = w0 * bfbits(h.z >> 16);
    acc[6] = w0 * bfbits(h.w & 0xffff); acc[7] = w0 * bfbits(h.w >> 16);
  }
  int e = off[i], e1 = off[i + 1];
  for (; e + 8 <= e1; e += 8) {
    int2 p0 = ew[e + 0], p1 = ew[e + 1], p2 = ew[e + 2], p3 = ew[e + 3];
    int2 p4 = ew[e + 4], p5 = ew[e + 5], p6 = ew[e + 6], p7 = ew[e + 7];
    uint4 g0 = *(const uint4*)(Hu + (size_t)p0.x * F1 + f0);
    uint4 g1 = *(const uint4*)(Hu + (size_t)p1.x * F1 + f0);
    uint4 g2 = *(const uint4*)(Hu + (size_t)p2.x * F1 + f0);
    uint4 g3 = *(const uint4*)(Hu + (size_t)p3.x * F1 + f0);
    uint4 g4 = *(const uint4*)(Hu + (size_t)p4.x * F1 + f0);
    uint4 g5 = *(const uint4*)(Hu + (size_t)p5.x * F1 + f0);
    uint4 g6 = *(const uint4*)(Hu + (size_t)p6.x * F1 + f0);
    uint4 g7 = *(const uint4*)(Hu + (size_t)p7.x * F1 + f0);
    accum8(acc, g0, __int_as_float(p0.y));
    accum8(acc, g1, __int_as_float(p1.y));
    accum8(acc, g2, __int_as_float(p2.y));
    accum8(acc, g3, __int_as_float(p3.y));
    accum8(acc, g4, __int_as_float(p4.y));
    accum8(acc, g5, __int_as_float(p5.y));
    accum8(acc, g6, __int_as_float(p6.y));
    accum8(acc, g7, __int_as_float(p7.y));
  }
  for (; e < e1; ++e) {
    int2 pe = ew[e];
    uint4 g = *(const uint4*)(Hu + (size_t)pe.x * F1 + f0);
    accum8(acc, g, __int_as_float(pe.y));
  }
  // bias + ReLU in registers
  float4 bb0 = *(const float4*)(b1 + f0);
  float4 bb1 = *(const float4*)(b1 + f0 + 4);
  float r8[8];
  r8[0] = fmaxf(acc[0] + bb0.x, 0.f); r8[1] = fmaxf(acc[1] + bb0.y, 0.f);
  r8[2] = fmaxf(acc[2] + bb0.z, 0.f); r8[3] = fmaxf(acc[3] + bb0.w, 0.f);
  r8[4] = fmaxf(acc[4] + bb1.x, 0.f); r8[5] = fmaxf(acc[5] + bb1.y, 0.f);
  r8[6] = fmaxf(acc[6] + bb1.z, 0.f); r8[7] = fmaxf(acc[7] + bb1.w, 0.f);
  // per-lane partial projection: p[c] = sum_f r8[f] * W2[f0+f][c]
  float p[16];
#pragma unroll
  for (int c = 0; c < 16; ++c) p[c] = 0.f;
#pragma unroll
  for (int f = 0; f < 8; ++f) {
    float rv = r8[f];
    const float4* wr = (const float4*)(W2 + (size_t)(f0 + f) * 16);
    float4 w0v = wr[0], w1v = wr[1], w2v = wr[2], w3v = wr[3];
    p[0]  = fmaf(rv, w0v.x, p[0]);  p[1]  = fmaf(rv, w0v.y, p[1]);
    p[2]  = fmaf(rv, w0v.z, p[2]);  p[3]  = fmaf(rv, w0v.w, p[3]);
    p[4]  = fmaf(rv, w1v.x, p[4]);  p[5]  = fmaf(rv, w1v.y, p[5]);
    p[6]  = fmaf(rv, w1v.z, p[6]);  p[7]  = fmaf(rv, w1v.w, p[7]);
    p[8]  = fmaf(rv, w2v.x, p[8]);  p[9]  = fmaf(rv, w2v.y, p[9]);
    p[10] = fmaf(rv, w2v.z, p[10]); p[11] = fmaf(rv, w2v.w, p[11]);
    p[12] = fmaf(rv, w3v.x, p[12]); p[13] = fmaf(rv, w3v.y, p[13]);
    p[14] = fmaf(rv, w3v.z, p[14]); p[15] = fmaf(rv, w3v.w, p[15]);
  }
  // fold-reduce across the 32-lane group; lane gl ends with column gl&15
#pragma unroll
  for (int c = 0; c < 16; ++c) p[c] += __shfl_xor(p[c], 16, 32);
#pragma unroll
  for (int c = 0; c < 8; ++c) {
    float keep = (gl & 8) ? p[c + 8] : p[c];
    float send = (gl & 8) ? p[c] : p[c + 8];
    p[c] = keep + __shfl_xor(send, 8, 32);
  }
#pragma unroll
  for (int c = 0; c < 4; ++c) {
    float keep = (gl & 4) ? p[c + 4] : p[c];
    float send = (gl & 4) ? p[c] : p[c + 4];
    p[c] = keep + __shfl_xor(send, 4, 32);
  }
#pragma unroll
  for (int c = 0; c < 2; ++c) {
    float keep = (gl & 2) ? p[c + 2] : p[c];
    float send = (gl & 2) ? p[c] : p[c + 2];
    p[c] = keep + __shfl_xor(send, 2, 32);
  }
  {
    float keep = (gl & 1) ? p[1] : p[0];
    float send = (gl & 1) ? p[0] : p[1];
    p[0] = keep + __shfl_xor(send, 1, 32);
  }
  if ((gl & 16) == 0 && idx < N)
    h2[(size_t)i * F2 + gl] = p[0];
}

// ---------------- Aggregation, 16 features (layer 2) ----------------

__global__ __launch_bounds__(256) void k_agg16(const float* __restrict__ H,
                                               const int* __restrict__ off,
                                               const int2* __restrict__ ew,
                                               const float* __restrict__ dinv,
                                               const float* __restrict__ bias,
                                               const int* __restrict__ perm,
                                               float* __restrict__ O, int N) {
  int t = threadIdx.x;
  int idx = blockIdx.x * 16 + (t >> 4);
  int f = t & 15;
  if (idx >= N) return;
  int i = perm[idx];
  float di = dinv[i];
  float acc = di * di * H[(size_t)i * F2 + f];
  int e = off[i], e1 = off[i + 1];
  for (; e + 4 <= e1; e += 4) {
    int2 p0 = ew[e + 0], p1 = ew[e + 1], p2 = ew[e + 2], p3 = ew[e + 3];
    float g0 = H[(size_t)p0.x * F2 + f];
    float g1 = H[(size_t)p1.x * F2 + f];
    float g2 = H[(size_t)p2.x * F2 + f];
    float g3 = H[(size_t)p3.x * F2 + f];
    acc = fmaf(__int_as_float(p0.y), g0, acc);
    acc = fmaf(__int_as_float(p1.y), g1, acc);
    acc = fmaf(__int_as_float(p2.y), g2, acc);
    acc = fmaf(__int_as_float(p3.y), g3, acc);
  }
  for (; e < e1; ++e) {
    int2 pe = ew[e];
    acc = fmaf(__int_as_float(pe.y), H[(size_t)pe.x * F2 + f], acc);
  }
  acc = fmaxf(acc + bias[f], 0.f);
  O[(size_t)i * F2 + f] = acc;
}

// ---------------- agg(out2) + GEMM3 + bias + log_softmax fused -------------

__global__ __launch_bounds__(256) void k_agg3_g3(const float* __restrict__ H,
                                                 const int* __restrict__ off,
                                                 const int2* __restrict__ ew,
                                                 const float* __restrict__ dinv,
                                                 const float* __restrict__ W3,
                                                 const float* __restrict__ b3,
                                                 const int* __restrict__ perm,
                                                 float* __restrict__ O, int N) {
  __shared__ float W3s[F2 * F3];
  __shared__ float b3s[F3];
  __shared__ float aggs[16 * 17];
  int t = threadIdx.x;
  for (int idx2 = t; idx2 < F2 * F3; idx2 += 256) W3s[idx2] = W3[idx2];
  if (t < F3) b3s[t] = b3[t];
  __syncthreads();

  int node = t >> 4, f = t & 15;
  int idx = blockIdx.x * 16 + node;
  if (idx >= N) return;
  int i = perm[idx];
  float di = dinv[i];
  float acc = di * di * H[(size_t)i * F2 + f];
  int e = off[i], e1 = off[i + 1];
  for (; e + 4 <= e1; e += 4) {
    int2 p0 = ew[e + 0], p1 = ew[e + 1], p2 = ew[e + 2], p3 = ew[e + 3];
    float g0 = H[(size_t)p0.x * F2 + f];
    float g1 = H[(size_t)p1.x * F2 + f];
    float g2 = H[(size_t)p2.x * F2 + f];
    float g3 = H[(size_t)p3.x * F2 + f];
    acc = fmaf(__int_as_float(p0.y), g0, acc);
    acc = fmaf(__int_as_float(p1.y), g1, acc);
    acc = fmaf(__int_as_float(p2.y), g2, acc);
    acc = fmaf(__int_as_float(p3.y), g3, acc);
  }
  for (; e < e1; ++e) {
    int2 pe = ew[e];
    acc = fmaf(__int_as_float(pe.y), H[(size_t)pe.x * F2 + f], acc);
  }
  aggs[node * 17 + f] = acc;

  const float* ar = &aggs[node * 17];
  float o0 = b3s[f], o1 = b3s[f + 16], o2 = (f < 8) ? b3s[f + 32] : 0.f;
#pragma unroll
  for (int k = 0; k < F2; ++k) {
    float a = ar[k];
    o0 = fmaf(a, W3s[k * F3 + f], o0);
    o1 = fmaf(a, W3s[k * F3 + f + 16], o1);
    if (f < 8) o2 = fmaf(a, W3s[k * F3 + f + 32], o2);
  }
  float m = fmaxf(o0, o1);
  if (f < 8) m = fmaxf(m, o2);
#pragma unroll
  for (int d = 1; d < 16; d <<= 1) m = fmaxf(m, __shfl_xor(m, d, 16));
  float s = __expf(o0 - m) + __expf(o1 - m) + ((f < 8) ? __expf(o2 - m) : 0.f);
#pragma unroll
  for (int d = 1; d < 16; d <<= 1) s += __shfl_xor(s, d, 16);
  float lse = m + __logf(s);
  float* orow = O + (size_t)i * F3;
  orow[f] = o0 - lse;
  orow[f + 16] = o1 - lse;
  if (f < 8) orow[f + 32] = o2 - lse;
}

// ---------------- launch ----------------

extern "C" void kernel_launch(void* const* d_in, const int* in_sizes, int n_in,
                              void* d_out, int out_size, void* d_ws, size_t ws_size,
                              hipStream_t stream) {
  const float* x  = (const float*)d_in[0];
  const int*   ei = (const int*)d_in[1];
  const float* W1 = (const float*)d_in[2];
  const float* b1 = (const float*)d_in[3];
  const float* W2 = (const float*)d_in[4];
  const float* b2 = (const float*)d_in[5];
  const float* W3 = (const float*)d_in[6];
  const float* b3 = (const float*)d_in[7];
  float* out = (float*)d_out;

  int N = in_sizes[0] / KIN;
  int E = in_sizes[1] / 2;

  char* p = (char*)d_ws;
  auto take = [&](size_t bytes) {
    char* r = p;
    p += (bytes + 255) & ~(size_t)255;
    return r;
  };
  int*   flag  = (int*)take(4);
  int*   cnt   = (int*)take((size_t)N * 4);
  int*   off   = (int*)take((size_t)(N + 1) * 4);
  float* dinv  = (float*)take((size_t)N * 4);
  int*   bsum  = (int*)take(64 * 4);
  int*   hist  = (int*)take(NBIN * 4);
  int*   binoff= (int*)take(NBIN * 4);
  int*   perm  = (int*)take((size_t)N * 4);
  int*   rank  = (int*)take((size_t)E * 4);
  int2*  ew    = (int2*)take((size_t)E * 8);
  unsigned short* w1t = (unsigned short*)take((size_t)KIN * F1 * 2);
  bf16*  h1    = (bf16*)take((size_t)N * F1 * 2);
  float* h2    = (float*)take((size_t)N * F2 * 4);
  float* out2  = (float*)take((size_t)N * F2 * 4);

  int nb  = (N + 255) / 256;
  int ebk = (E + 255) / 256;
  int nsc = (N + 1023) / 1024;

  k_init2<<<nb + 128, 256, 0, stream>>>(cnt, ei, flag, W1, w1t, hist, N, nb);
  k_count<<<ebk, 256, 0, stream>>>(ei, flag, cnt, rank, E);
  k_scan1<<<nsc, 256, 0, stream>>>(cnt, off, bsum, dinv, hist, N);
  k_scan3m<<<nsc, 256, 0, stream>>>(off, bsum, hist, binoff, N);

  int ngx = (N + 127) / 128;
  k_gemm1_sc<<<ngx * 2 + ebk + nb, 256, 0, stream>>>(x, w1t, h1, N, ngx,
                                                     ei, flag, off, rank, dinv, ew, E, ebk,
                                                     cnt, binoff, perm);

  k_agg1g2<<<(N + 7) / 8, 256, 0, stream>>>(h1, off, ew, dinv, b1, perm, W2, h2, N);
  k_agg16<<<(N + 15) / 16, 256, 0, stream>>>(h2, off, ew, dinv, b2, perm, out2, N);
  k_agg3_g3<<<(N + 15) / 16, 256, 0, stream>>>(out2, off, ew, dinv, W3, b3, perm, out, N);
}

// Round 5
// 331.666 us; speedup vs baseline: 1.2525x; 1.2525x over previous
//
#include <hip/hip_runtime.h>
#include <hip/hip_bf16.h>
#include <math.h>

typedef __hip_bfloat16 bf16;
typedef __attribute__((ext_vector_type(8))) __bf16 bf16x8;
typedef __attribute__((ext_vector_type(4))) float f32x4;

#define KIN 512
#define F1  256
#define F2  16
#define F3  40
#define NBIN 64
#define TSS 264   // Ts row stride in floats: 16B-aligned, offsets wave groups by 8 banks

// ---------------- helpers ----------------

__device__ inline unsigned pk_bf2(float a, float b) {
  bf16 x = __float2bfloat16(a), y = __float2bfloat16(b);
  unsigned short ux = *(unsigned short*)&x, uy = *(unsigned short*)&y;
  return (unsigned)ux | ((unsigned)uy << 16);
}
__device__ inline float bfbits(unsigned u16) {
  unsigned v = u16 << 16;
  return *(float*)&v;
}
__device__ inline void async16(const void* g, void* l) {
  __builtin_amdgcn_global_load_lds((const __attribute__((address_space(1))) void*)g,
                                   (__attribute__((address_space(3))) void*)l, 16, 0, 0);
}
__device__ inline void accum8(float* acc, uint4 h, float w) {
  acc[0] = fmaf(w, bfbits(h.x & 0xffff), acc[0]);
  acc[1] = fmaf(w, bfbits(h.x >> 16),    acc[1]);
  acc[2] = fmaf(w, bfbits(h.y & 0xffff), acc[2]);
  acc[3] = fmaf(w, bfbits(h.y >> 16),    acc[3]);
  acc[4] = fmaf(w, bfbits(h.z & 0xffff), acc[4]);
  acc[5] = fmaf(w, bfbits(h.z >> 16),    acc[5]);
  acc[6] = fmaf(w, bfbits(h.w & 0xffff), acc[6]);
  acc[7] = fmaf(w, bfbits(h.w >> 16),    acc[7]);
}

// ---------------- init: zero cnt + hist + flag + W1 transpose (fused) ------

__global__ __launch_bounds__(256) void k_init2(int* __restrict__ cnt,
                                               const int* __restrict__ ei, int* __restrict__ flag,
                                               const float* __restrict__ W,
                                               unsigned short* __restrict__ Wt,
                                               int* __restrict__ hist,
                                               int n, int nb) {
  int b = blockIdx.x;
  int t = threadIdx.x;
  if (b < nb) {
    int i = b * 256 + t;
    if (i < n) cnt[i] = 0;
    if (b == 0 && t < NBIN) hist[t] = 0;
    if (b == 0 && t == 0)
      *flag = (ei[1] == 0 && ei[3] == 0 && ei[5] == 0 && ei[7] == 0) ? 1 : 0;
  } else {
    __shared__ float tile[32][33];
    int b2 = b - nb;
    int k0 = (b2 & 15) * 32;
    int n0 = (b2 >> 4) * 32;
    int lr = t >> 5, lc = t & 31;
#pragma unroll
    for (int rr = 0; rr < 32; rr += 8)
      tile[lr + rr][lc] = W[(size_t)(k0 + lr + rr) * F1 + n0 + lc];
    __syncthreads();
#pragma unroll
    for (int rr = 0; rr < 32; rr += 8) {
      bf16 v = __float2bfloat16(tile[lc][lr + rr]);
      Wt[(size_t)(n0 + lr + rr) * KIN + k0 + lc] = *(unsigned short*)&v;
    }
  }
}

// ---- count (atomic, returns rank) interleaved with x f32->bf16 streaming ---

__global__ __launch_bounds__(256) void k_count_conv(const int* __restrict__ ei,
                                                    const int* __restrict__ flag,
                                                    int* __restrict__ cnt,
                                                    int* __restrict__ rank,
                                                    int E, int nct, int stride,
                                                    const float* __restrict__ X,
                                                    unsigned short* __restrict__ Xb,
                                                    int total8) {
  int b = blockIdx.x;
  int t = threadIdx.x;
  bool is_cnt = (b % stride == 0) && (b / stride < nct);
  if (is_cnt) {
    int e = (b / stride) * 256 + t;
    if (e >= E) return;
    int is64 = *flag;
    int d = is64 ? ei[2 * E + 2 * e] : ei[E + e];
    rank[e] = atomicAdd(&cnt[d], 1);
  } else {
    int nb_before = (b + stride - 1) / stride;
    if (nb_before > nct) nb_before = nct;
    int idx = (b - nb_before) * 256 + t;
    if (idx >= total8) return;
    const float4* src = (const float4*)X + (size_t)idx * 2;
    float4 f0 = src[0], f1 = src[1];
    uint4 pk;
    pk.x = pk_bf2(f0.x, f0.y); pk.y = pk_bf2(f0.z, f0.w);
    pk.z = pk_bf2(f1.x, f1.y); pk.w = pk_bf2(f1.z, f1.w);
    ((uint4*)Xb)[idx] = pk;
  }
}

__global__ __launch_bounds__(256) void k_scan1(const int* __restrict__ cnt,
                                               int* __restrict__ off,
                                               int* __restrict__ bsum,
                                               float* __restrict__ dinv,
                                               int* __restrict__ hist, int N) {
  __shared__ int s[256];
  __shared__ int lh[NBIN];
  int t = threadIdx.x;
  if (t < NBIN) lh[t] = 0;
  int base = blockIdx.x * 1024 + t * 4;
  int v0 = (base + 0 < N) ? cnt[base + 0] : 0;
  int v1 = (base + 1 < N) ? cnt[base + 1] : 0;
  int v2 = (base + 2 < N) ? cnt[base + 2] : 0;
  int v3 = (base + 3 < N) ? cnt[base + 3] : 0;
  if (base + 0 < N) dinv[base + 0] = rsqrtf((float)(v0 + 1));
  if (base + 1 < N) dinv[base + 1] = rsqrtf((float)(v1 + 1));
  if (base + 2 < N) dinv[base + 2] = rsqrtf((float)(v2 + 1));
  if (base + 3 < N) dinv[base + 3] = rsqrtf((float)(v3 + 1));
  int tsum = v0 + v1 + v2 + v3;
  s[t] = tsum;
  __syncthreads();
  // degree histogram (LDS-aggregated, lh zeroed before the sync above)
  if (base + 0 < N) atomicAdd(&lh[v0 < 63 ? v0 : 63], 1);
  if (base + 1 < N) atomicAdd(&lh[v1 < 63 ? v1 : 63], 1);
  if (base + 2 < N) atomicAdd(&lh[v2 < 63 ? v2 : 63], 1);
  if (base + 3 < N) atomicAdd(&lh[v3 < 63 ? v3 : 63], 1);
  for (int d = 1; d < 256; d <<= 1) {
    int u = (t >= d) ? s[t - d] : 0;
    __syncthreads();
    s[t] += u;
    __syncthreads();
  }
  int excl = s[t] - tsum;
  int p0 = excl + v0, p1 = p0 + v1, p2 = p1 + v2, p3 = p2 + v3;
  if (base + 0 < N) off[base + 1] = p0;
  if (base + 1 < N) off[base + 2] = p1;
  if (base + 2 < N) off[base + 3] = p2;
  if (base + 3 < N) off[base + 4] = p3;
  if (t == 255) bsum[blockIdx.x] = s[255];
  // last scan-loop __syncthreads() ordered all lh atomics before this read
  if (t < NBIN) {
    int h = lh[t];
    if (h) atomicAdd(&hist[t], h);
  }
}

// scan3 with inlined carry reduction + DESCENDING degree-bin exclusive scan
// (high-degree nodes first in perm -> heavy blocks launch first, no drain tail)
__global__ __launch_bounds__(256) void k_scan3m(int* __restrict__ off,
                                                const int* __restrict__ bsum,
                                                const int* __restrict__ hist,
                                                int* __restrict__ binoff, int N) {
  __shared__ int cs;
  int t = threadIdx.x;
  if (t < 64) {
    int v = (t < blockIdx.x) ? bsum[t] : 0;   // blockIdx.x <= 49 < 64
    for (int d = 32; d; d >>= 1) v += __shfl_xor(v, d, 64);
    if (t == 0) cs = v;
  }
  if (blockIdx.x == 0 && t < NBIN) {
    int a = 0;
    for (int j = t + 1; j < NBIN; ++j) a += hist[j];
    binoff[t] = a;
  }
  __syncthreads();
  int c = cs;
  int base = blockIdx.x * 1024 + t * 4;
#pragma unroll
  for (int k = 0; k < 4; ++k)
    if (base + k < N) off[base + k + 1] += c;
  if (blockIdx.x == 0 && t == 0) off[0] = 0;
}

// ---------------- GEMM1 (m97 structure) + scatter + perm-build, role-fused -
// gemm role: col-tile fastest + bijective XCD-chunk swizzle (m204) so both
// col-tiles sharing an A row-panel run adjacently on the SAME XCD -> the
// second A-panel read is an L2 hit (xb re-read 102 MB -> ~51 MB).

__global__ __launch_bounds__(256) void k_gemm1_sc(const unsigned short* __restrict__ Ab,
                                                  const unsigned short* __restrict__ Bt,
                                                  bf16* __restrict__ C, int M, int ngx,
                                                  const int* __restrict__ ei,
                                                  const int* __restrict__ flag,
                                                  const int* __restrict__ off,
                                                  const int* __restrict__ rank,
                                                  const float* __restrict__ dinv,
                                                  int2* __restrict__ ew, int E, int ebk,
                                                  const int* __restrict__ cnt,
                                                  int* __restrict__ binoff,
                                                  int* __restrict__ perm) {
  __shared__ unsigned short As[128 * 32];
  __shared__ unsigned short Bs[128 * 32];
  __shared__ int lh[NBIN], lb[NBIN];
  int b = blockIdx.x;
  int t = threadIdx.x;
  int ngemm = ngx * 2;
  if (b >= ngemm + ebk) {
    // ---- perm-build role: counting-sort scatter (nodes sorted by degree) ----
    int idx = (b - ngemm - ebk) * 256 + t;
    if (t < NBIN) lh[t] = 0;
    __syncthreads();
    int bin = 0, lr2 = 0;
    bool valid = (idx < M);
    if (valid) {
      int d = cnt[idx];
      bin = d < 63 ? d : 63;
      lr2 = atomicAdd(&lh[bin], 1);
    }
    __syncthreads();
    if (t < NBIN && lh[t] > 0) lb[t] = atomicAdd(&binoff[t], lh[t]);
    __syncthreads();
    if (valid) perm[lb[bin] + lr2] = idx;
    return;
  }
  if (b >= ngemm) {
    // ---- scatter role (atomic-free) ----
    int e = (b - ngemm) * 256 + t;
    if (e >= E) return;
    int is64 = *flag;
    int s, d;
    if (is64) { s = ei[2 * e]; d = ei[2 * E + 2 * e]; }
    else      { s = ei[e];     d = ei[E + e]; }
    int pos = off[d] + rank[e];
    float w = dinv[s] * dinv[d];
    ew[pos] = make_int2(s, __float_as_int(w));
    return;
  }
  // ---- gemm role ----
  // bijective XCD-chunk swizzle over [0, ngemm): XCD x owns a contiguous
  // chunk of logical ids; logical&1 = col-tile (fastest) so the A-panel
  // pair lands back-to-back on one XCD.
  int qq = ngemm >> 3, rr = ngemm & 7;
  int xcd = b & 7, kk = b >> 3;
  int logical = (xcd < rr ? xcd * (qq + 1) : rr * (qq + 1) + (xcd - rr) * qq) + kk;
  int wave = t >> 6, lane = t & 63;
  int wm = wave >> 1, wn = wave & 1;
  int row0 = (logical >> 1) * 128, col0 = (logical & 1) * 128;
  int q = lane >> 4, m16 = lane & 15;
  int srow = lane >> 2, schk = lane & 3;

  f32x4 acc[4][4];
#pragma unroll
  for (int i = 0; i < 4; ++i)
#pragma unroll
    for (int j = 0; j < 4; ++j) acc[i][j] = {0.f, 0.f, 0.f, 0.f};

  for (int kb = 0; kb < 16; ++kb) {
    __syncthreads();
#pragma unroll
    for (int jj = 0; jj < 2; ++jj) {
      int lr = wave * 32 + jj * 16 + srow;
      int gr = row0 + lr; if (gr >= M) gr = M - 1;
      int gchk = schk ^ ((lr >> 1) & 3);
      async16(Ab + (size_t)gr * KIN + kb * 32 + gchk * 8,
              As + (wave * 32 + jj * 16) * 32);
    }
#pragma unroll
    for (int jj = 0; jj < 2; ++jj) {
      int lr = wave * 32 + jj * 16 + srow;
      int gchk = schk ^ ((lr >> 1) & 3);
      async16(Bt + (size_t)(col0 + lr) * KIN + kb * 32 + gchk * 8,
              Bs + (wave * 32 + jj * 16) * 32);
    }
    __syncthreads();
    bf16x8 af[4], bfr[4];
#pragma unroll
    for (int i = 0; i < 4; ++i) {
      int m = wm * 64 + i * 16 + m16;
      af[i] = *(const bf16x8*)(As + m * 32 + ((q ^ ((m >> 1) & 3)) * 8));
    }
#pragma unroll
    for (int j = 0; j < 4; ++j) {
      int n = wn * 64 + j * 16 + m16;
      bfr[j] = *(const bf16x8*)(Bs + n * 32 + ((q ^ ((n >> 1) & 3)) * 8));
    }
#pragma unroll
    for (int j = 0; j < 4; ++j)
#pragma unroll
      for (int i = 0; i < 4; ++i)
        acc[i][j] = __builtin_amdgcn_mfma_f32_16x16x32_bf16(af[i], bfr[j], acc[i][j], 0, 0, 0);
  }

#pragma unroll
  for (int i = 0; i < 4; ++i) {
#pragma unroll
    for (int r = 0; r < 4; ++r) {
      int row = row0 + wm * 64 + i * 16 + q * 4 + r;
      if (row < M) {
#pragma unroll
        for (int j = 0; j < 4; ++j) {
          int col = col0 + wn * 64 + j * 16 + m16;
          C[(size_t)row * F1 + col] = __float2bfloat16(acc[i][j][r]);
        }
      }
    }
  }
}

// ------- Fused Aggregation L1 (full 256-feat rows) + ReLU + GEMM2 ----------
// 8 nodes/block, 32 lanes/node (lane owns 8 feats). Each edge gathers one
// full 512B row. out1 never touches HBM: bias+ReLU -> LDS -> 256x16 GEMM2.
// GEMM2 phase uses ALL 256 threads (split-k by 2, combined with one
// intra-wave shfl_xor; no extra barrier).

__global__ __launch_bounds__(256) void k_agg1g2(const bf16* __restrict__ H,
                                                const int* __restrict__ off,
                                                const int2* __restrict__ ew,
                                                const float* __restrict__ dinv,
                                                const float* __restrict__ b1,
                                                const int* __restrict__ perm,
                                                const float* __restrict__ W2,
                                                float* __restrict__ h2, int N) {
  __shared__ float W2s[F1 * F2];     // 16 KB
  __shared__ float Ts[8][TSS];       // 8.25 KB, stride offsets groups by 8 banks
  int t = threadIdx.x;
#pragma unroll
  for (int j = 0; j < 16; ++j) W2s[t + 256 * j] = W2[t + 256 * j];
  int idx = blockIdx.x * 8 + (t >> 5);
  int cidx = idx < N ? idx : N - 1;
  int i = perm[cidx];
  int f0 = (t & 31) * 8;
  const unsigned short* Hu = (const unsigned short*)H;
  float di = dinv[i];
  float w0 = di * di;
  float acc[8];
  {
    uint4 h = *(const uint4*)(Hu + (size_t)i * F1 + f0);
    acc[0] = w0 * bfbits(h.x & 0xffff); acc[1] = w0 * bfbits(h.x >> 16);
    acc[2] = w0 * bfbits(h.y & 0xffff); acc[3] = w0 * bfbits(h.y >> 16);
    acc[4] = w0 * bfbits(h.z & 0xffff); acc[5] = w0 * bfbits(h.z >> 16);
    acc[6] = w0 * bfbits(h.w & 0xffff); acc[7] = w0 * bfbits(h.w >> 16);
  }
  int e = off[i], e1 = off[i + 1];
  for (; e + 8 <= e1; e += 8) {
    int2 p0 = ew[e + 0], p1 = ew[e + 1], p2 = ew[e + 2], p3 = ew[e + 3];
    int2 p4 = ew[e + 4], p5 = ew[e + 5], p6 = ew[e + 6], p7 = ew[e + 7];
    uint4 g0 = *(const uint4*)(Hu + (size_t)p0.x * F1 + f0);
    uint4 g1 = *(const uint4*)(Hu + (size_t)p1.x * F1 + f0);
    uint4 g2 = *(const uint4*)(Hu + (size_t)p2.x * F1 + f0);
    uint4 g3 = *(const uint4*)(Hu + (size_t)p3.x * F1 + f0);
    uint4 g4 = *(const uint4*)(Hu + (size_t)p4.x * F1 + f0);
    uint4 g5 = *(const uint4*)(Hu + (size_t)p5.x * F1 + f0);
    uint4 g6 = *(const uint4*)(Hu + (size_t)p6.x * F1 + f0);
    uint4 g7 = *(const uint4*)(Hu + (size_t)p7.x * F1 + f0);
    accum8(acc, g0, __int_as_float(p0.y));
    accum8(acc, g1, __int_as_float(p1.y));
    accum8(acc, g2, __int_as_float(p2.y));
    accum8(acc, g3, __int_as_float(p3.y));
    accum8(acc, g4, __int_as_float(p4.y));
    accum8(acc, g5, __int_as_float(p5.y));
    accum8(acc, g6, __int_as_float(p6.y));
    accum8(acc, g7, __int_as_float(p7.y));
  }
  for (; e < e1; ++e) {
    int2 pe = ew[e];
    uint4 g = *(const uint4*)(Hu + (size_t)pe.x * F1 + f0);
    accum8(acc, g, __int_as_float(pe.y));
  }
  // bias + ReLU -> LDS (f32, never rounded to bf16)
  float4 bb0 = *(const float4*)(b1 + f0);
  float4 bb1 = *(const float4*)(b1 + f0 + 4);
  int node = t >> 5;
  float* ts = &Ts[node][f0];
  ts[0] = fmaxf(acc[0] + bb0.x, 0.f);
  ts[1] = fmaxf(acc[1] + bb0.y, 0.f);
  ts[2] = fmaxf(acc[2] + bb0.z, 0.f);
  ts[3] = fmaxf(acc[3] + bb0.w, 0.f);
  ts[4] = fmaxf(acc[4] + bb1.x, 0.f);
  ts[5] = fmaxf(acc[5] + bb1.y, 0.f);
  ts[6] = fmaxf(acc[6] + bb1.z, 0.f);
  ts[7] = fmaxf(acc[7] + bb1.w, 0.f);
  __syncthreads();
  // GEMM2 phase, all 256 threads: node = t>>5, col = t&15, half = (t>>4)&1.
  // half h covers k in [h*128, h*128+128); partners are lanes l and l^16 of
  // the same 32-lane group -> combine with one shfl_xor, no barrier.
  {
    int n2 = t >> 5, c = t & 15, half = (t >> 4) & 1;
    int gi = blockIdx.x * 8 + n2;
    float s = 0.f;
    const float4* tv = (const float4*)&Ts[n2][half * 128];
    const float* W2h = W2s + half * 128 * 16;
#pragma unroll 8
    for (int k4 = 0; k4 < 32; ++k4) {
      float4 a = tv[k4];
      int k = k4 * 4;
      s = fmaf(a.x, W2h[(k + 0) * 16 + c], s);
      s = fmaf(a.y, W2h[(k + 1) * 16 + c], s);
      s = fmaf(a.z, W2h[(k + 2) * 16 + c], s);
      s = fmaf(a.w, W2h[(k + 3) * 16 + c], s);
    }
    s += __shfl_xor(s, 16, 32);
    if (half == 0 && gi < N) h2[(size_t)perm[gi] * F2 + c] = s;
  }
}

// ---------------- Aggregation, 16 features (layer 2) ----------------

__global__ __launch_bounds__(256) void k_agg16(const float* __restrict__ H,
                                               const int* __restrict__ off,
                                               const int2* __restrict__ ew,
                                               const float* __restrict__ dinv,
                                               const float* __restrict__ bias,
                                               const int* __restrict__ perm,
                                               float* __restrict__ O, int N) {
  int t = threadIdx.x;
  int idx = blockIdx.x * 16 + (t >> 4);
  int f = t & 15;
  if (idx >= N) return;
  int i = perm[idx];
  float di = dinv[i];
  float acc = di * di * H[(size_t)i * F2 + f];
  int e = off[i], e1 = off[i + 1];
  for (; e + 4 <= e1; e += 4) {
    int2 p0 = ew[e + 0], p1 = ew[e + 1], p2 = ew[e + 2], p3 = ew[e + 3];
    float g0 = H[(size_t)p0.x * F2 + f];
    float g1 = H[(size_t)p1.x * F2 + f];
    float g2 = H[(size_t)p2.x * F2 + f];
    float g3 = H[(size_t)p3.x * F2 + f];
    acc = fmaf(__int_as_float(p0.y), g0, acc);
    acc = fmaf(__int_as_float(p1.y), g1, acc);
    acc = fmaf(__int_as_float(p2.y), g2, acc);
    acc = fmaf(__int_as_float(p3.y), g3, acc);
  }
  for (; e < e1; ++e) {
    int2 pe = ew[e];
    acc = fmaf(__int_as_float(pe.y), H[(size_t)pe.x * F2 + f], acc);
  }
  acc = fmaxf(acc + bias[f], 0.f);
  O[(size_t)i * F2 + f] = acc;
}

// ---------------- agg(out2) + GEMM3 + bias + log_softmax fused -------------

__global__ __launch_bounds__(256) void k_agg3_g3(const float* __restrict__ H,
                                                 const int* __restrict__ off,
                                                 const int2* __restrict__ ew,
                                                 const float* __restrict__ dinv,
                                                 const float* __restrict__ W3,
                                                 const float* __restrict__ b3,
                                                 const int* __restrict__ perm,
                                                 float* __restrict__ O, int N) {
  __shared__ float W3s[F2 * F3];
  __shared__ float b3s[F3];
  __shared__ float aggs[16 * 17];
  int t = threadIdx.x;
  for (int idx2 = t; idx2 < F2 * F3; idx2 += 256) W3s[idx2] = W3[idx2];
  if (t < F3) b3s[t] = b3[t];
  __syncthreads();

  int node = t >> 4, f = t & 15;
  int idx = blockIdx.x * 16 + node;
  if (idx >= N) return;
  int i = perm[idx];
  float di = dinv[i];
  float acc = di * di * H[(size_t)i * F2 + f];
  int e = off[i], e1 = off[i + 1];
  for (; e + 4 <= e1; e += 4) {
    int2 p0 = ew[e + 0], p1 = ew[e + 1], p2 = ew[e + 2], p3 = ew[e + 3];
    float g0 = H[(size_t)p0.x * F2 + f];
    float g1 = H[(size_t)p1.x * F2 + f];
    float g2 = H[(size_t)p2.x * F2 + f];
    float g3 = H[(size_t)p3.x * F2 + f];
    acc = fmaf(__int_as_float(p0.y), g0, acc);
    acc = fmaf(__int_as_float(p1.y), g1, acc);
    acc = fmaf(__int_as_float(p2.y), g2, acc);
    acc = fmaf(__int_as_float(p3.y), g3, acc);
  }
  for (; e < e1; ++e) {
    int2 pe = ew[e];
    acc = fmaf(__int_as_float(pe.y), H[(size_t)pe.x * F2 + f], acc);
  }
  aggs[node * 17 + f] = acc;

  const float* ar = &aggs[node * 17];
  float o0 = b3s[f], o1 = b3s[f + 16], o2 = (f < 8) ? b3s[f + 32] : 0.f;
#pragma unroll
  for (int k = 0; k < F2; ++k) {
    float a = ar[k];
    o0 = fmaf(a, W3s[k * F3 + f], o0);
    o1 = fmaf(a, W3s[k * F3 + f + 16], o1);
    if (f < 8) o2 = fmaf(a, W3s[k * F3 + f + 32], o2);
  }
  float m = fmaxf(o0, o1);
  if (f < 8) m = fmaxf(m, o2);
#pragma unroll
  for (int d = 1; d < 16; d <<= 1) m = fmaxf(m, __shfl_xor(m, d, 16));
  float s = __expf(o0 - m) + __expf(o1 - m) + ((f < 8) ? __expf(o2 - m) : 0.f);
#pragma unroll
  for (int d = 1; d < 16; d <<= 1) s += __shfl_xor(s, d, 16);
  float lse = m + __logf(s);
  float* orow = O + (size_t)i * F3;
  orow[f] = o0 - lse;
  orow[f + 16] = o1 - lse;
  if (f < 8) orow[f + 32] = o2 - lse;
}

// ---------------- launch ----------------

extern "C" void kernel_launch(void* const* d_in, const int* in_sizes, int n_in,
                              void* d_out, int out_size, void* d_ws, size_t ws_size,
                              hipStream_t stream) {
  const float* x  = (const float*)d_in[0];
  const int*   ei = (const int*)d_in[1];
  const float* W1 = (const float*)d_in[2];
  const float* b1 = (const float*)d_in[3];
  const float* W2 = (const float*)d_in[4];
  const float* b2 = (const float*)d_in[5];
  const float* W3 = (const float*)d_in[6];
  const float* b3 = (const float*)d_in[7];
  float* out = (float*)d_out;

  int N = in_sizes[0] / KIN;
  int E = in_sizes[1] / 2;

  char* p = (char*)d_ws;
  auto take = [&](size_t bytes) {
    char* r = p;
    p += (bytes + 255) & ~(size_t)255;
    return r;
  };
  int*   flag  = (int*)take(4);
  int*   cnt   = (int*)take((size_t)N * 4);
  int*   off   = (int*)take((size_t)(N + 1) * 4);
  float* dinv  = (float*)take((size_t)N * 4);
  int*   bsum  = (int*)take(64 * 4);
  int*   hist  = (int*)take(NBIN * 4);
  int*   binoff= (int*)take(NBIN * 4);
  int*   perm  = (int*)take((size_t)N * 4);
  int*   rank  = (int*)take((size_t)E * 4);
  int2*  ew    = (int2*)take((size_t)E * 8);
  unsigned short* w1t = (unsigned short*)take((size_t)KIN * F1 * 2);
  unsigned short* xb  = (unsigned short*)take((size_t)N * KIN * 2);
  bf16*  h1    = (bf16*)take((size_t)N * F1 * 2);
  float* h2    = (float*)take((size_t)N * F2 * 4);
  float* out2  = (float*)take((size_t)N * F2 * 4);

  int nb  = (N + 255) / 256;
  int ebk = (E + 255) / 256;
  int nsc = (N + 1023) / 1024;
  int total8 = (N * KIN) / 8;
  int cvb = (total8 + 255) / 256;
  int tot = ebk + cvb;
  int stride = tot / ebk; if (stride < 1) stride = 1;

  k_init2<<<nb + 128, 256, 0, stream>>>(cnt, ei, flag, W1, w1t, hist, N, nb);
  k_count_conv<<<tot, 256, 0, stream>>>(ei, flag, cnt, rank, E, ebk, stride, x, xb, total8);
  k_scan1<<<nsc, 256, 0, stream>>>(cnt, off, bsum, dinv, hist, N);
  k_scan3m<<<nsc, 256, 0, stream>>>(off, bsum, hist, binoff, N);

  int ngx = (N + 127) / 128;
  k_gemm1_sc<<<ngx * 2 + ebk + nb, 256, 0, stream>>>(xb, w1t, h1, N, ngx,
                                                     ei, flag, off, rank, dinv, ew, E, ebk,
                                                     cnt, binoff, perm);

  k_agg1g2<<<(N + 7) / 8, 256, 0, stream>>>(h1, off, ew, dinv, b1, perm, W2, h2, N);
  k_agg16<<<(N + 15) / 16, 256, 0, stream>>>(h2, off, ew, dinv, b2, perm, out2, N);
  k_agg3_g3<<<(N + 15) / 16, 256, 0, stream>>>(out2, off, ew, dinv, W3, b3, perm, out, N);
}

// Round 6
// 320.969 us; speedup vs baseline: 1.2943x; 1.0333x over previous
//
#include <hip/hip_runtime.h>
#include <hip/hip_bf16.h>
#include <math.h>

typedef __hip_bfloat16 bf16;
typedef __attribute__((ext_vector_type(8))) __bf16 bf16x8;
typedef __attribute__((ext_vector_type(4))) float f32x4;

#define KIN 512
#define F1  256
#define F2  16
#define F3  40
#define NBIN 64
#define TSS 264   // Ts row stride in floats: 16B-aligned, offsets wave groups by 8 banks

// ---------------- helpers ----------------

__device__ inline unsigned pk_bf2(float a, float b) {
  bf16 x = __float2bfloat16(a), y = __float2bfloat16(b);
  unsigned short ux = *(unsigned short*)&x, uy = *(unsigned short*)&y;
  return (unsigned)ux | ((unsigned)uy << 16);
}
__device__ inline float bfbits(unsigned u16) {
  unsigned v = u16 << 16;
  return *(float*)&v;
}
__device__ inline void async16(const void* g, void* l) {
  __builtin_amdgcn_global_load_lds((const __attribute__((address_space(1))) void*)g,
                                   (__attribute__((address_space(3))) void*)l, 16, 0, 0);
}
__device__ inline void accum8(float* acc, uint4 h, float w) {
  acc[0] = fmaf(w, bfbits(h.x & 0xffff), acc[0]);
  acc[1] = fmaf(w, bfbits(h.x >> 16),    acc[1]);
  acc[2] = fmaf(w, bfbits(h.y & 0xffff), acc[2]);
  acc[3] = fmaf(w, bfbits(h.y >> 16),    acc[3]);
  acc[4] = fmaf(w, bfbits(h.z & 0xffff), acc[4]);
  acc[5] = fmaf(w, bfbits(h.z >> 16),    acc[5]);
  acc[6] = fmaf(w, bfbits(h.w & 0xffff), acc[6]);
  acc[7] = fmaf(w, bfbits(h.w >> 16),    acc[7]);
}

// ---------------- init: zero cnt + hist + flag + W1 transpose (fused) ------

__global__ __launch_bounds__(256) void k_init2(int* __restrict__ cnt,
                                               const int* __restrict__ ei, int* __restrict__ flag,
                                               const float* __restrict__ W,
                                               unsigned short* __restrict__ Wt,
                                               int* __restrict__ hist,
                                               int n, int nb) {
  int b = blockIdx.x;
  int t = threadIdx.x;
  if (b < nb) {
    int i = b * 256 + t;
    if (i < n) cnt[i] = 0;
    if (b == 0 && t < NBIN) hist[t] = 0;
    if (b == 0 && t == 0)
      *flag = (ei[1] == 0 && ei[3] == 0 && ei[5] == 0 && ei[7] == 0) ? 1 : 0;
  } else {
    __shared__ float tile[32][33];
    int b2 = b - nb;
    int k0 = (b2 & 15) * 32;
    int n0 = (b2 >> 4) * 32;
    int lr = t >> 5, lc = t & 31;
#pragma unroll
    for (int rr = 0; rr < 32; rr += 8)
      tile[lr + rr][lc] = W[(size_t)(k0 + lr + rr) * F1 + n0 + lc];
    __syncthreads();
#pragma unroll
    for (int rr = 0; rr < 32; rr += 8) {
      bf16 v = __float2bfloat16(tile[lc][lr + rr]);
      Wt[(size_t)(n0 + lr + rr) * KIN + k0 + lc] = *(unsigned short*)&v;
    }
  }
}

// ---- count (atomic, returns rank) interleaved with x f32->bf16 streaming ---

__global__ __launch_bounds__(256) void k_count_conv(const int* __restrict__ ei,
                                                    const int* __restrict__ flag,
                                                    int* __restrict__ cnt,
                                                    int* __restrict__ rank,
                                                    int E, int nct, int stride,
                                                    const float* __restrict__ X,
                                                    unsigned short* __restrict__ Xb,
                                                    int total8) {
  int b = blockIdx.x;
  int t = threadIdx.x;
  bool is_cnt = (b % stride == 0) && (b / stride < nct);
  if (is_cnt) {
    int e = (b / stride) * 256 + t;
    if (e >= E) return;
    int is64 = *flag;
    int d = is64 ? ei[2 * E + 2 * e] : ei[E + e];
    rank[e] = atomicAdd(&cnt[d], 1);
  } else {
    int nb_before = (b + stride - 1) / stride;
    if (nb_before > nct) nb_before = nct;
    int idx = (b - nb_before) * 256 + t;
    if (idx >= total8) return;
    const float4* src = (const float4*)X + (size_t)idx * 2;
    float4 f0 = src[0], f1 = src[1];
    uint4 pk;
    pk.x = pk_bf2(f0.x, f0.y); pk.y = pk_bf2(f0.z, f0.w);
    pk.z = pk_bf2(f1.x, f1.y); pk.w = pk_bf2(f1.z, f1.w);
    ((uint4*)Xb)[idx] = pk;
  }
}

__global__ __launch_bounds__(256) void k_scan1(const int* __restrict__ cnt,
                                               int* __restrict__ off,
                                               int* __restrict__ bsum,
                                               float* __restrict__ dinv,
                                               int* __restrict__ hist, int N) {
  __shared__ int s[256];
  __shared__ int lh[NBIN];
  int t = threadIdx.x;
  if (t < NBIN) lh[t] = 0;
  int base = blockIdx.x * 1024 + t * 4;
  int v0 = (base + 0 < N) ? cnt[base + 0] : 0;
  int v1 = (base + 1 < N) ? cnt[base + 1] : 0;
  int v2 = (base + 2 < N) ? cnt[base + 2] : 0;
  int v3 = (base + 3 < N) ? cnt[base + 3] : 0;
  if (base + 0 < N) dinv[base + 0] = rsqrtf((float)(v0 + 1));
  if (base + 1 < N) dinv[base + 1] = rsqrtf((float)(v1 + 1));
  if (base + 2 < N) dinv[base + 2] = rsqrtf((float)(v2 + 1));
  if (base + 3 < N) dinv[base + 3] = rsqrtf((float)(v3 + 1));
  int tsum = v0 + v1 + v2 + v3;
  s[t] = tsum;
  __syncthreads();
  // degree histogram (LDS-aggregated, lh zeroed before the sync above)
  if (base + 0 < N) atomicAdd(&lh[v0 < 63 ? v0 : 63], 1);
  if (base + 1 < N) atomicAdd(&lh[v1 < 63 ? v1 : 63], 1);
  if (base + 2 < N) atomicAdd(&lh[v2 < 63 ? v2 : 63], 1);
  if (base + 3 < N) atomicAdd(&lh[v3 < 63 ? v3 : 63], 1);
  for (int d = 1; d < 256; d <<= 1) {
    int u = (t >= d) ? s[t - d] : 0;
    __syncthreads();
    s[t] += u;
    __syncthreads();
  }
  int excl = s[t] - tsum;
  int p0 = excl + v0, p1 = p0 + v1, p2 = p1 + v2, p3 = p2 + v3;
  if (base + 0 < N) off[base + 1] = p0;
  if (base + 1 < N) off[base + 2] = p1;
  if (base + 2 < N) off[base + 3] = p2;
  if (base + 3 < N) off[base + 4] = p3;
  if (t == 255) bsum[blockIdx.x] = s[255];
  // last scan-loop __syncthreads() ordered all lh atomics before this read
  if (t < NBIN) {
    int h = lh[t];
    if (h) atomicAdd(&hist[t], h);
  }
}

// scan3 with inlined carry reduction + DESCENDING degree-bin exclusive scan
// (high-degree nodes first in perm -> heavy blocks launch first, no drain tail)
__global__ __launch_bounds__(256) void k_scan3m(int* __restrict__ off,
                                                const int* __restrict__ bsum,
                                                const int* __restrict__ hist,
                                                int* __restrict__ binoff, int N) {
  __shared__ int cs;
  int t = threadIdx.x;
  if (t < 64) {
    int v = (t < blockIdx.x) ? bsum[t] : 0;   // blockIdx.x <= 49 < 64
    for (int d = 32; d; d >>= 1) v += __shfl_xor(v, d, 64);
    if (t == 0) cs = v;
  }
  if (blockIdx.x == 0 && t < NBIN) {
    int a = 0;
    for (int j = t + 1; j < NBIN; ++j) a += hist[j];
    binoff[t] = a;
  }
  __syncthreads();
  int c = cs;
  int base = blockIdx.x * 1024 + t * 4;
#pragma unroll
  for (int k = 0; k < 4; ++k)
    if (base + k < N) off[base + k + 1] += c;
  if (blockIdx.x == 0 && t == 0) off[0] = 0;
}

// ---------------- GEMM1 (m97 structure) + scatter + perm-build, role-fused -
// gemm role: col-tile fastest + bijective XCD-chunk swizzle (m204) so both
// col-tiles sharing an A row-panel run adjacently on the SAME XCD -> the
// second A-panel read is an L2 hit.

__global__ __launch_bounds__(256) void k_gemm1_sc(const unsigned short* __restrict__ Ab,
                                                  const unsigned short* __restrict__ Bt,
                                                  bf16* __restrict__ C, int M, int ngx,
                                                  const int* __restrict__ ei,
                                                  const int* __restrict__ flag,
                                                  const int* __restrict__ off,
                                                  const int* __restrict__ rank,
                                                  const float* __restrict__ dinv,
                                                  int2* __restrict__ ew, int E, int ebk,
                                                  const int* __restrict__ cnt,
                                                  int* __restrict__ binoff,
                                                  int* __restrict__ perm) {
  __shared__ unsigned short As[128 * 32];
  __shared__ unsigned short Bs[128 * 32];
  __shared__ int lh[NBIN], lb[NBIN];
  int b = blockIdx.x;
  int t = threadIdx.x;
  int ngemm = ngx * 2;
  if (b >= ngemm + ebk) {
    // ---- perm-build role: counting-sort scatter (nodes sorted by degree) ----
    int idx = (b - ngemm - ebk) * 256 + t;
    if (t < NBIN) lh[t] = 0;
    __syncthreads();
    int bin = 0, lr2 = 0;
    bool valid = (idx < M);
    if (valid) {
      int d = cnt[idx];
      bin = d < 63 ? d : 63;
      lr2 = atomicAdd(&lh[bin], 1);
    }
    __syncthreads();
    if (t < NBIN && lh[t] > 0) lb[t] = atomicAdd(&binoff[t], lh[t]);
    __syncthreads();
    if (valid) perm[lb[bin] + lr2] = idx;
    return;
  }
  if (b >= ngemm) {
    // ---- scatter role (atomic-free) ----
    int e = (b - ngemm) * 256 + t;
    if (e >= E) return;
    int is64 = *flag;
    int s, d;
    if (is64) { s = ei[2 * e]; d = ei[2 * E + 2 * e]; }
    else      { s = ei[e];     d = ei[E + e]; }
    int pos = off[d] + rank[e];
    float w = dinv[s] * dinv[d];
    ew[pos] = make_int2(s, __float_as_int(w));
    return;
  }
  // ---- gemm role ----
  // bijective XCD-chunk swizzle over [0, ngemm): XCD x owns a contiguous
  // chunk of logical ids; logical&1 = col-tile (fastest) so the A-panel
  // pair lands back-to-back on one XCD.
  int qq = ngemm >> 3, rr = ngemm & 7;
  int xcd = b & 7, kk = b >> 3;
  int logical = (xcd < rr ? xcd * (qq + 1) : rr * (qq + 1) + (xcd - rr) * qq) + kk;
  int wave = t >> 6, lane = t & 63;
  int wm = wave >> 1, wn = wave & 1;
  int row0 = (logical >> 1) * 128, col0 = (logical & 1) * 128;
  int q = lane >> 4, m16 = lane & 15;
  int srow = lane >> 2, schk = lane & 3;

  f32x4 acc[4][4];
#pragma unroll
  for (int i = 0; i < 4; ++i)
#pragma unroll
    for (int j = 0; j < 4; ++j) acc[i][j] = {0.f, 0.f, 0.f, 0.f};

  for (int kb = 0; kb < 16; ++kb) {
    __syncthreads();
#pragma unroll
    for (int jj = 0; jj < 2; ++jj) {
      int lr = wave * 32 + jj * 16 + srow;
      int gr = row0 + lr; if (gr >= M) gr = M - 1;
      int gchk = schk ^ ((lr >> 1) & 3);
      async16(Ab + (size_t)gr * KIN + kb * 32 + gchk * 8,
              As + (wave * 32 + jj * 16) * 32);
    }
#pragma unroll
    for (int jj = 0; jj < 2; ++jj) {
      int lr = wave * 32 + jj * 16 + srow;
      int gchk = schk ^ ((lr >> 1) & 3);
      async16(Bt + (size_t)(col0 + lr) * KIN + kb * 32 + gchk * 8,
              Bs + (wave * 32 + jj * 16) * 32);
    }
    __syncthreads();
    bf16x8 af[4], bfr[4];
#pragma unroll
    for (int i = 0; i < 4; ++i) {
      int m = wm * 64 + i * 16 + m16;
      af[i] = *(const bf16x8*)(As + m * 32 + ((q ^ ((m >> 1) & 3)) * 8));
    }
#pragma unroll
    for (int j = 0; j < 4; ++j) {
      int n = wn * 64 + j * 16 + m16;
      bfr[j] = *(const bf16x8*)(Bs + n * 32 + ((q ^ ((n >> 1) & 3)) * 8));
    }
#pragma unroll
    for (int j = 0; j < 4; ++j)
#pragma unroll
      for (int i = 0; i < 4; ++i)
        acc[i][j] = __builtin_amdgcn_mfma_f32_16x16x32_bf16(af[i], bfr[j], acc[i][j], 0, 0, 0);
  }

#pragma unroll
  for (int i = 0; i < 4; ++i) {
#pragma unroll
    for (int r = 0; r < 4; ++r) {
      int row = row0 + wm * 64 + i * 16 + q * 4 + r;
      if (row < M) {
#pragma unroll
        for (int j = 0; j < 4; ++j) {
          int col = col0 + wn * 64 + j * 16 + m16;
          C[(size_t)row * F1 + col] = __float2bfloat16(acc[i][j][r]);
        }
      }
    }
  }
}

// ------- Fused Aggregation L1 (full 256-feat rows) + ReLU + GEMM2 ----------
// 8 nodes/block, 32 lanes/node (lane owns 8 feats). Each edge gathers one
// full 512B row: half the gather-request count of the 2-phase split, and
// ew/off/perm/dinv/self-row are read ONCE. out1 never touches HBM: after
// bias+ReLU the activations go to LDS and are multiplied by W2 in-block.
// GEMM2 phase: 128 threads, broadcast-clean LDS reads (R5's split-k variant
// caused 10M bank conflicts = +16us; reverted).

__global__ __launch_bounds__(256) void k_agg1g2(const bf16* __restrict__ H,
                                                const int* __restrict__ off,
                                                const int2* __restrict__ ew,
                                                const float* __restrict__ dinv,
                                                const float* __restrict__ b1,
                                                const int* __restrict__ perm,
                                                const float* __restrict__ W2,
                                                float* __restrict__ h2, int N) {
  __shared__ float W2s[F1 * F2];     // 16 KB
  __shared__ float Ts[8][TSS];       // 8.25 KB, stride offsets groups by 8 banks
  int t = threadIdx.x;
#pragma unroll
  for (int j = 0; j < 16; ++j) W2s[t + 256 * j] = W2[t + 256 * j];
  int idx = blockIdx.x * 8 + (t >> 5);
  int cidx = idx < N ? idx : N - 1;
  int i = perm[cidx];
  int f0 = (t & 31) * 8;
  const unsigned short* Hu = (const unsigned short*)H;
  float di = dinv[i];
  float w0 = di * di;
  float acc[8];
  {
    uint4 h = *(const uint4*)(Hu + (size_t)i * F1 + f0);
    acc[0] = w0 * bfbits(h.x & 0xffff); acc[1] = w0 * bfbits(h.x >> 16);
    acc[2] = w0 * bfbits(h.y & 0xffff); acc[3] = w0 * bfbits(h.y >> 16);
    acc[4] = w0 * bfbits(h.z & 0xffff); acc[5] = w0 * bfbits(h.z >> 16);
    acc[6] = w0 * bfbits(h.w & 0xffff); acc[7] = w0 * bfbits(h.w >> 16);
  }
  int e = off[i], e1 = off[i + 1];
  for (; e + 8 <= e1; e += 8) {
    int2 p0 = ew[e + 0], p1 = ew[e + 1], p2 = ew[e + 2], p3 = ew[e + 3];
    int2 p4 = ew[e + 4], p5 = ew[e + 5], p6 = ew[e + 6], p7 = ew[e + 7];
    uint4 g0 = *(const uint4*)(Hu + (size_t)p0.x * F1 + f0);
    uint4 g1 = *(const uint4*)(Hu + (size_t)p1.x * F1 + f0);
    uint4 g2 = *(const uint4*)(Hu + (size_t)p2.x * F1 + f0);
    uint4 g3 = *(const uint4*)(Hu + (size_t)p3.x * F1 + f0);
    uint4 g4 = *(const uint4*)(Hu + (size_t)p4.x * F1 + f0);
    uint4 g5 = *(const uint4*)(Hu + (size_t)p5.x * F1 + f0);
    uint4 g6 = *(const uint4*)(Hu + (size_t)p6.x * F1 + f0);
    uint4 g7 = *(const uint4*)(Hu + (size_t)p7.x * F1 + f0);
    accum8(acc, g0, __int_as_float(p0.y));
    accum8(acc, g1, __int_as_float(p1.y));
    accum8(acc, g2, __int_as_float(p2.y));
    accum8(acc, g3, __int_as_float(p3.y));
    accum8(acc, g4, __int_as_float(p4.y));
    accum8(acc, g5, __int_as_float(p5.y));
    accum8(acc, g6, __int_as_float(p6.y));
    accum8(acc, g7, __int_as_float(p7.y));
  }
  for (; e < e1; ++e) {
    int2 pe = ew[e];
    uint4 g = *(const uint4*)(Hu + (size_t)pe.x * F1 + f0);
    accum8(acc, g, __int_as_float(pe.y));
  }
  // bias + ReLU -> LDS (f32, never rounded to bf16)
  float4 bb0 = *(const float4*)(b1 + f0);
  float4 bb1 = *(const float4*)(b1 + f0 + 4);
  int node = t >> 5;
  float* ts = &Ts[node][f0];
  ts[0] = fmaxf(acc[0] + bb0.x, 0.f);
  ts[1] = fmaxf(acc[1] + bb0.y, 0.f);
  ts[2] = fmaxf(acc[2] + bb0.z, 0.f);
  ts[3] = fmaxf(acc[3] + bb0.w, 0.f);
  ts[4] = fmaxf(acc[4] + bb1.x, 0.f);
  ts[5] = fmaxf(acc[5] + bb1.y, 0.f);
  ts[6] = fmaxf(acc[6] + bb1.z, 0.f);
  ts[7] = fmaxf(acc[7] + bb1.w, 0.f);
  __syncthreads();
  // GEMM2 phase: 128 threads, node = t>>4, c = t&15
  if (t < 128) {
    int n2 = t >> 4, c = t & 15;
    int gi = blockIdx.x * 8 + n2;
    float s = 0.f;
    const float4* tv = (const float4*)&Ts[n2][0];
#pragma unroll 8
    for (int k4 = 0; k4 < 64; ++k4) {
      float4 a = tv[k4];
      int k = k4 * 4;
      s = fmaf(a.x, W2s[(k + 0) * 16 + c], s);
      s = fmaf(a.y, W2s[(k + 1) * 16 + c], s);
      s = fmaf(a.z, W2s[(k + 2) * 16 + c], s);
      s = fmaf(a.w, W2s[(k + 3) * 16 + c], s);
    }
    if (gi < N) h2[(size_t)perm[gi] * F2 + c] = s;
  }
}

// ---------------- Aggregation, 16 features (layer 2) ----------------

__global__ __launch_bounds__(256) void k_agg16(const float* __restrict__ H,
                                               const int* __restrict__ off,
                                               const int2* __restrict__ ew,
                                               const float* __restrict__ dinv,
                                               const float* __restrict__ bias,
                                               const int* __restrict__ perm,
                                               float* __restrict__ O, int N) {
  int t = threadIdx.x;
  int idx = blockIdx.x * 16 + (t >> 4);
  int f = t & 15;
  if (idx >= N) return;
  int i = perm[idx];
  float di = dinv[i];
  float acc = di * di * H[(size_t)i * F2 + f];
  int e = off[i], e1 = off[i + 1];
  for (; e + 4 <= e1; e += 4) {
    int2 p0 = ew[e + 0], p1 = ew[e + 1], p2 = ew[e + 2], p3 = ew[e + 3];
    float g0 = H[(size_t)p0.x * F2 + f];
    float g1 = H[(size_t)p1.x * F2 + f];
    float g2 = H[(size_t)p2.x * F2 + f];
    float g3 = H[(size_t)p3.x * F2 + f];
    acc = fmaf(__int_as_float(p0.y), g0, acc);
    acc = fmaf(__int_as_float(p1.y), g1, acc);
    acc = fmaf(__int_as_float(p2.y), g2, acc);
    acc = fmaf(__int_as_float(p3.y), g3, acc);
  }
  for (; e < e1; ++e) {
    int2 pe = ew[e];
    acc = fmaf(__int_as_float(pe.y), H[(size_t)pe.x * F2 + f], acc);
  }
  acc = fmaxf(acc + bias[f], 0.f);
  O[(size_t)i * F2 + f] = acc;
}

// ---------------- agg(out2) + GEMM3 + bias + log_softmax fused -------------

__global__ __launch_bounds__(256) void k_agg3_g3(const float* __restrict__ H,
                                                 const int* __restrict__ off,
                                                 const int2* __restrict__ ew,
                                                 const float* __restrict__ dinv,
                                                 const float* __restrict__ W3,
                                                 const float* __restrict__ b3,
                                                 const int* __restrict__ perm,
                                                 float* __restrict__ O, int N) {
  __shared__ float W3s[F2 * F3];
  __shared__ float b3s[F3];
  __shared__ float aggs[16 * 17];
  int t = threadIdx.x;
  for (int idx2 = t; idx2 < F2 * F3; idx2 += 256) W3s[idx2] = W3[idx2];
  if (t < F3) b3s[t] = b3[t];
  __syncthreads();

  int node = t >> 4, f = t & 15;
  int idx = blockIdx.x * 16 + node;
  if (idx >= N) return;
  int i = perm[idx];
  float di = dinv[i];
  float acc = di * di * H[(size_t)i * F2 + f];
  int e = off[i], e1 = off[i + 1];
  for (; e + 4 <= e1; e += 4) {
    int2 p0 = ew[e + 0], p1 = ew[e + 1], p2 = ew[e + 2], p3 = ew[e + 3];
    float g0 = H[(size_t)p0.x * F2 + f];
    float g1 = H[(size_t)p1.x * F2 + f];
    float g2 = H[(size_t)p2.x * F2 + f];
    float g3 = H[(size_t)p3.x * F2 + f];
    acc = fmaf(__int_as_float(p0.y), g0, acc);
    acc = fmaf(__int_as_float(p1.y), g1, acc);
    acc = fmaf(__int_as_float(p2.y), g2, acc);
    acc = fmaf(__int_as_float(p3.y), g3, acc);
  }
  for (; e < e1; ++e) {
    int2 pe = ew[e];
    acc = fmaf(__int_as_float(pe.y), H[(size_t)pe.x * F2 + f], acc);
  }
  aggs[node * 17 + f] = acc;

  const float* ar = &aggs[node * 17];
  float o0 = b3s[f], o1 = b3s[f + 16], o2 = (f < 8) ? b3s[f + 32] : 0.f;
#pragma unroll
  for (int k = 0; k < F2; ++k) {
    float a = ar[k];
    o0 = fmaf(a, W3s[k * F3 + f], o0);
    o1 = fmaf(a, W3s[k * F3 + f + 16], o1);
    if (f < 8) o2 = fmaf(a, W3s[k * F3 + f + 32], o2);
  }
  float m = fmaxf(o0, o1);
  if (f < 8) m = fmaxf(m, o2);
#pragma unroll
  for (int d = 1; d < 16; d <<= 1) m = fmaxf(m, __shfl_xor(m, d, 16));
  float s = __expf(o0 - m) + __expf(o1 - m) + ((f < 8) ? __expf(o2 - m) : 0.f);
#pragma unroll
  for (int d = 1; d < 16; d <<= 1) s += __shfl_xor(s, d, 16);
  float lse = m + __logf(s);
  float* orow = O + (size_t)i * F3;
  orow[f] = o0 - lse;
  orow[f + 16] = o1 - lse;
  if (f < 8) orow[f + 32] = o2 - lse;
}

// ---------------- launch ----------------

extern "C" void kernel_launch(void* const* d_in, const int* in_sizes, int n_in,
                              void* d_out, int out_size, void* d_ws, size_t ws_size,
                              hipStream_t stream) {
  const float* x  = (const float*)d_in[0];
  const int*   ei = (const int*)d_in[1];
  const float* W1 = (const float*)d_in[2];
  const float* b1 = (const float*)d_in[3];
  const float* W2 = (const float*)d_in[4];
  const float* b2 = (const float*)d_in[5];
  const float* W3 = (const float*)d_in[6];
  const float* b3 = (const float*)d_in[7];
  float* out = (float*)d_out;

  int N = in_sizes[0] / KIN;
  int E = in_sizes[1] / 2;

  char* p = (char*)d_ws;
  auto take = [&](size_t bytes) {
    char* r = p;
    p += (bytes + 255) & ~(size_t)255;
    return r;
  };
  int*   flag  = (int*)take(4);
  int*   cnt   = (int*)take((size_t)N * 4);
  int*   off   = (int*)take((size_t)(N + 1) * 4);
  float* dinv  = (float*)take((size_t)N * 4);
  int*   bsum  = (int*)take(64 * 4);
  int*   hist  = (int*)take(NBIN * 4);
  int*   binoff= (int*)take(NBIN * 4);
  int*   perm  = (int*)take((size_t)N * 4);
  int*   rank  = (int*)take((size_t)E * 4);
  int2*  ew    = (int2*)take((size_t)E * 8);
  unsigned short* w1t = (unsigned short*)take((size_t)KIN * F1 * 2);
  unsigned short* xb  = (unsigned short*)take((size_t)N * KIN * 2);
  bf16*  h1    = (bf16*)take((size_t)N * F1 * 2);
  float* h2    = (float*)take((size_t)N * F2 * 4);
  float* out2  = (float*)take((size_t)N * F2 * 4);

  int nb  = (N + 255) / 256;
  int ebk = (E + 255) / 256;
  int nsc = (N + 1023) / 1024;
  int total8 = (N * KIN) / 8;
  int cvb = (total8 + 255) / 256;
  int tot = ebk + cvb;
  int stride = tot / ebk; if (stride < 1) stride = 1;

  k_init2<<<nb + 128, 256, 0, stream>>>(cnt, ei, flag, W1, w1t, hist, N, nb);
  k_count_conv<<<tot, 256, 0, stream>>>(ei, flag, cnt, rank, E, ebk, stride, x, xb, total8);
  k_scan1<<<nsc, 256, 0, stream>>>(cnt, off, bsum, dinv, hist, N);
  k_scan3m<<<nsc, 256, 0, stream>>>(off, bsum, hist, binoff, N);

  int ngx = (N + 127) / 128;
  k_gemm1_sc<<<ngx * 2 + ebk + nb, 256, 0, stream>>>(xb, w1t, h1, N, ngx,
                                                     ei, flag, off, rank, dinv, ew, E, ebk,
                                                     cnt, binoff, perm);

  k_agg1g2<<<(N + 7) / 8, 256, 0, stream>>>(h1, off, ew, dinv, b1, perm, W2, h2, N);
  k_agg16<<<(N + 15) / 16, 256, 0, stream>>>(h2, off, ew, dinv, b2, perm, out2, N);
  k_agg3_g3<<<(N + 15) / 16, 256, 0, stream>>>(out2, off, ew, dinv, W3, b3, perm, out, N);
}